// Round 7
// baseline (160.851 us; speedup 1.0000x reference)
//
#include <hip/hip_runtime.h>
#include <hip/hip_bf16.h>

#define M_DIM 4096
#define N_DIM 4096
#define K_DIM 4096

typedef __attribute__((ext_vector_type(8))) __bf16 bf16x8;
typedef __attribute__((ext_vector_type(8))) short short8;
typedef __attribute__((ext_vector_type(8))) unsigned short ushort8;
typedef __attribute__((ext_vector_type(16))) float f32x16;

// async global->LDS, 16B/lane (m104: dest = wave-uniform base + lane*16)
__device__ __forceinline__ void gload_lds16(const void* g, void* l) {
    __builtin_amdgcn_global_load_lds(
        (const __attribute__((address_space(1))) void*)g,
        (__attribute__((address_space(3))) void*)l,
        16, 0, 0);
}

__device__ __forceinline__ bf16x8 ld8(const unsigned short* p) {
    short8 r = *reinterpret_cast<const short8*>(p);
    return __builtin_bit_cast(bf16x8, r);
}

// ---------------------------------------------------------------------------
// fused fp32->bf16 conversion: x (pruned) and w (unpruned) in ONE launch
// ---------------------------------------------------------------------------
__global__ void prune_cvt2(const float* __restrict__ x,
                           const float* __restrict__ w,
                           unsigned short* __restrict__ xb,
                           unsigned short* __restrict__ wb,
                           const float* __restrict__ thrp, int n8) {
    const float thr = thrp[0];
    const int stride = gridDim.x * blockDim.x;
    const int total = 2 * n8;
    for (int idx = blockIdx.x * blockDim.x + threadIdx.x; idx < total; idx += stride) {
        const bool isx = idx < n8;
        const int j = isx ? idx : idx - n8;
        const float* src = isx ? x : w;
        unsigned short* dst = isx ? xb : wb;
        const float te = isx ? thr : -1.0f;   // |v| > -1 always true -> keep all
        const float4* p = reinterpret_cast<const float4*>(src) + 2 * (size_t)j;
        float4 v0 = p[0];
        float4 v1 = p[1];
        float v[8] = {v0.x, v0.y, v0.z, v0.w, v1.x, v1.y, v1.z, v1.w};
        ushort8 o;
#pragma unroll
        for (int e = 0; e < 8; ++e) {
            float f = v[e];
            f = (fabsf(f) > te) ? f : 0.0f;   // prune in fp32 (exact predicate)
            __hip_bfloat16 hh = __float2bfloat16(f);
            o[e] = *reinterpret_cast<unsigned short*>(&hh);
        }
        *reinterpret_cast<ushort8*>(dst + 8 * (size_t)j) = o;
    }
}

// ---------------------------------------------------------------------------
// C = A * B^T, 256x256 tile, BK=64, 8 waves, 32x32x16 MFMA, 4-phase/K-tile
// pipeline (R6 skeleton: reg-level frag double-buffering, ONE barrier/phase,
// t-loop unrolled x2 for compile-time LDS bases).
//
// Per wave: 128x64 output = 4 row-blocks (rb) x 2 col-blocks (nb) of 32x32.
// Phase q computes rb q: 8 MFMA (2 nb x 4 k-slices of 16). B's 8 frags are
// read once per tile at ph0; A rb-frags are read one phase ahead; ph3
// pre-reads rb0 of tile t+1 (<- SA'0, landed per ledger).
//
// vmcnt ledger (identical to R6; issues ph0 +4 B', ph1 +2 A'01, ph2 +2 A'23):
//   ph0-end vmcnt(5) lands A2(t) -> ph1 reads rb2
//   ph1-end vmcnt(6) lands A3(t) -> ph2 reads rb3
//   ph2-end vmcnt(3) lands B'x4+A0' -> ph3 pre-reads rb0(t+1)
//   ph3-end vmcnt(2) lands A1'     -> next ph0 reads rb1(t+1) + B(t+1)
// Never drains to 0 in the loop.
//
// LDS per buffer: A[256][64], B[256][64], slot-swizzled:
//   element(row, logical col c) at row*64 + 8*((c>>3) ^ (row&7)) + (c&7)
// ---------------------------------------------------------------------------
__global__ __launch_bounds__(512, 2) void gemm_8phase(
        const unsigned short* __restrict__ A,
        const unsigned short* __restrict__ B,
        float* __restrict__ C) {
    __shared__ __align__(16) unsigned short lds[65536];  // 128 KB

    const int tid  = threadIdx.x;
    const int lane = tid & 63;
    const int wid  = tid >> 6;
    const int wr   = wid >> 2;   // 0..1 : 128-row strip
    const int wc   = wid & 3;    // 0..3 : 64-col strip

    // XCD-aware bijective swizzle (256 blocks / 8 XCDs)
    const int bid = blockIdx.x;
    const int swz = (bid & 7) * 32 + (bid >> 3);
    const int bm = (swz >> 4) * 256;
    const int bn = (swz & 15) * 256;

    // staging: A-half ah staged by threads [ah*256, +256); load j = rows [32j,+32)
    const int g  = tid & 255;
    const int ah = tid >> 8;
    const int arow = bm + ah * 128 + (g >> 3);
    const int acol = 8 * ((g & 7) ^ ((g >> 3) & 7));      // pre-swizzled source col
    const unsigned short* Asrc = A + (size_t)arow * K_DIM + acol;
    const int AdstE = ah * 8192 + g * 8;

    const int h = lane + 64 * wr;
    const int brow = bn + wc * 64 + (h >> 3);
    const int bcol = 8 * ((h & 7) ^ ((h >> 3) & 7));
    const unsigned short* Bsrc = B + (size_t)brow * K_DIM + bcol;
    const int BdstE = wc * 4096 + h * 8;

#define SA(dstb, j, kg) gload_lds16(Asrc + (size_t)(32*(j))*K_DIM + (kg), (dstb) + AdstE + 2048*(j))
#define SB(dstb, j, kg) gload_lds16(Bsrc + (size_t)(16*(j))*K_DIM + (kg), (dstb) + BdstE + 1024*(j))

    // 32x32 fragment addressing: row = lane&31, k = 8*(lane>>5) + e
    const int fr32 = lane & 31;
    const int kq2  = lane >> 5;
    const int rowOffA = (wr * 128 + fr32) * 64;
    const int rowOffB = (wc * 64 + fr32) * 64;
    // k-slice s (16 wide): logical slot = 2s + kq2, physical = slot ^ (row&7)
    const int sk_0 = 8 * ((0 + kq2) ^ (fr32 & 7));
    const int sk_1 = 8 * ((2 + kq2) ^ (fr32 & 7));
    const int sk_2 = 8 * ((4 + kq2) ^ (fr32 & 7));
    const int sk_3 = 8 * ((6 + kq2) ^ (fr32 & 7));

    f32x16 acc[4][2] = {};   // [rb][nb]
    bf16x8 bfr[2][4];        // [nb][slice]

#define MFMA8(rb, P0, P1, P2, P3)                                                                  \
    __builtin_amdgcn_s_setprio(1);                                                                 \
    acc[rb][0] = __builtin_amdgcn_mfma_f32_32x32x16_bf16(P0, bfr[0][0], acc[rb][0], 0, 0, 0);      \
    acc[rb][1] = __builtin_amdgcn_mfma_f32_32x32x16_bf16(P0, bfr[1][0], acc[rb][1], 0, 0, 0);      \
    acc[rb][0] = __builtin_amdgcn_mfma_f32_32x32x16_bf16(P1, bfr[0][1], acc[rb][0], 0, 0, 0);      \
    acc[rb][1] = __builtin_amdgcn_mfma_f32_32x32x16_bf16(P1, bfr[1][1], acc[rb][1], 0, 0, 0);      \
    acc[rb][0] = __builtin_amdgcn_mfma_f32_32x32x16_bf16(P2, bfr[0][2], acc[rb][0], 0, 0, 0);      \
    acc[rb][1] = __builtin_amdgcn_mfma_f32_32x32x16_bf16(P2, bfr[1][2], acc[rb][1], 0, 0, 0);      \
    acc[rb][0] = __builtin_amdgcn_mfma_f32_32x32x16_bf16(P3, bfr[0][3], acc[rb][0], 0, 0, 0);      \
    acc[rb][1] = __builtin_amdgcn_mfma_f32_32x32x16_bf16(P3, bfr[1][3], acc[rb][1], 0, 0, 0);      \
    __builtin_amdgcn_s_setprio(0);

    // One K-tile: phases rb0..rb3; identical ledger to R6.
#define TILE_BODY(Ab, Bb, AbN, BbN, kn)                                                            \
    {                                                                                              \
        /* ph0: MFMA rb0 (p); read B(t) 8 + rb1 (q); stage B'x4 */                                 \
        bfr[0][0] = ld8((Bb) + rowOffB + 0 * 2048 + sk_0);                                         \
        bfr[0][1] = ld8((Bb) + rowOffB + 0 * 2048 + sk_1);                                         \
        bfr[0][2] = ld8((Bb) + rowOffB + 0 * 2048 + sk_2);                                         \
        bfr[0][3] = ld8((Bb) + rowOffB + 0 * 2048 + sk_3);                                         \
        bfr[1][0] = ld8((Bb) + rowOffB + 1 * 2048 + sk_0);                                         \
        bfr[1][1] = ld8((Bb) + rowOffB + 1 * 2048 + sk_1);                                         \
        bfr[1][2] = ld8((Bb) + rowOffB + 1 * 2048 + sk_2);                                         \
        bfr[1][3] = ld8((Bb) + rowOffB + 1 * 2048 + sk_3);                                         \
        bf16x8 q0 = ld8((Ab) + rowOffA + 2048 + sk_0);                                             \
        bf16x8 q1 = ld8((Ab) + rowOffA + 2048 + sk_1);                                             \
        bf16x8 q2 = ld8((Ab) + rowOffA + 2048 + sk_2);                                             \
        bf16x8 q3 = ld8((Ab) + rowOffA + 2048 + sk_3);                                             \
        SB((BbN), 0, (kn)); SB((BbN), 1, (kn)); SB((BbN), 2, (kn)); SB((BbN), 3, (kn));            \
        MFMA8(0, p0, p1, p2, p3);                                                                  \
        asm volatile("s_waitcnt vmcnt(5)" ::: "memory");                                           \
        asm volatile("s_barrier" ::: "memory");                                                    \
        /* ph1: MFMA rb1 (q); read rb2 (r); stage A'0,A'1 */                                       \
        bf16x8 r0 = ld8((Ab) + rowOffA + 4096 + sk_0);                                             \
        bf16x8 r1 = ld8((Ab) + rowOffA + 4096 + sk_1);                                             \
        bf16x8 r2 = ld8((Ab) + rowOffA + 4096 + sk_2);                                             \
        bf16x8 r3 = ld8((Ab) + rowOffA + 4096 + sk_3);                                             \
        SA((AbN), 0, (kn)); SA((AbN), 1, (kn));                                                    \
        MFMA8(1, q0, q1, q2, q3);                                                                  \
        asm volatile("s_waitcnt vmcnt(6)" ::: "memory");                                           \
        asm volatile("s_barrier" ::: "memory");                                                    \
        /* ph2: MFMA rb2 (r); read rb3 (s); stage A'2,A'3 */                                       \
        bf16x8 s0 = ld8((Ab) + rowOffA + 6144 + sk_0);                                             \
        bf16x8 s1 = ld8((Ab) + rowOffA + 6144 + sk_1);                                             \
        bf16x8 s2 = ld8((Ab) + rowOffA + 6144 + sk_2);                                             \
        bf16x8 s3 = ld8((Ab) + rowOffA + 6144 + sk_3);                                             \
        SA((AbN), 2, (kn)); SA((AbN), 3, (kn));                                                    \
        MFMA8(2, r0, r1, r2, r3);                                                                  \
        asm volatile("s_waitcnt vmcnt(3)" ::: "memory");                                           \
        asm volatile("s_barrier" ::: "memory");                                                    \
        /* ph3: MFMA rb3 (s); pre-read rb0(t+1) from next buf */                                   \
        p0 = ld8((AbN) + rowOffA + 0 + sk_0);                                                      \
        p1 = ld8((AbN) + rowOffA + 0 + sk_1);                                                      \
        p2 = ld8((AbN) + rowOffA + 0 + sk_2);                                                      \
        p3 = ld8((AbN) + rowOffA + 0 + sk_3);                                                      \
        MFMA8(3, s0, s1, s2, s3);                                                                  \
        asm volatile("s_waitcnt vmcnt(2)" ::: "memory");                                           \
        asm volatile("s_barrier" ::: "memory");                                                    \
    }

    // compile-time buffer bases
    unsigned short* A0 = lds;
    unsigned short* A1 = lds + 16384;
    unsigned short* B0 = lds + 32768;
    unsigned short* B1 = lds + 49152;

    // ---- prologue: stage tile0 into buf0; land B0-3,A0,A1; pre-read rb0 frags
    SB(B0, 0, 0); SB(B0, 1, 0); SB(B0, 2, 0); SB(B0, 3, 0);
    SA(A0, 0, 0); SA(A0, 1, 0); SA(A0, 2, 0); SA(A0, 3, 0);
    asm volatile("s_waitcnt vmcnt(2)" ::: "memory");
    asm volatile("s_barrier" ::: "memory");

    bf16x8 p0 = ld8(A0 + rowOffA + sk_0);
    bf16x8 p1 = ld8(A0 + rowOffA + sk_1);
    bf16x8 p2 = ld8(A0 + rowOffA + sk_2);
    bf16x8 p3 = ld8(A0 + rowOffA + sk_3);

    for (int t = 0; t < 64; t += 2) {
        const int kn0 = (t + 1) * 64;                     // stage for tile t+1
        const int kn1 = (t + 2 < 64 ? t + 2 : 63) * 64;   // clamp: tail stage is dead
        TILE_BODY(A0, B0, A1, B1, kn0);   // even tile: read buf0, stage buf1
        TILE_BODY(A1, B1, A0, B0, kn1);   // odd tile:  read buf1, stage buf0
    }

    asm volatile("s_waitcnt vmcnt(0)" ::: "memory");  // drain dead tail stages

    // C/D layout 32x32 (m74/m101): col = lane&31, row = (reg&3)+8*(reg>>2)+4*(lane>>5)
    const int ccol = bn + wc * 64 + fr32;
    const int rbase = bm + wr * 128 + 4 * kq2;
#pragma unroll
    for (int rb = 0; rb < 4; ++rb)
#pragma unroll
        for (int nb = 0; nb < 2; ++nb)
#pragma unroll
            for (int reg = 0; reg < 16; ++reg) {
                const int row = rbase + rb * 32 + (reg & 3) + 8 * (reg >> 2);
                C[(size_t)row * N_DIM + ccol + nb * 32] = acc[rb][nb][reg];
            }
}

// ---------------------------------------------------------------------------
// fp32 fallback (only if ws too small)
// ---------------------------------------------------------------------------
__global__ void gemm_f32_fallback(const float* __restrict__ A,
                                  const float* __restrict__ B,
                                  float* __restrict__ C,
                                  const float* __restrict__ thrp) {
    __shared__ float As[32][33];
    __shared__ float Bs[32][33];
    const float thr = thrp[0];
    const int tx = threadIdx.x, ty = threadIdx.y;
    const int row = blockIdx.y * 32 + ty;
    float acc = 0.0f;
    for (int k0 = 0; k0 < K_DIM; k0 += 32) {
        float a = A[(size_t)row * K_DIM + k0 + tx];
        As[ty][tx] = (fabsf(a) > thr) ? a : 0.0f;
        Bs[ty][tx] = B[(size_t)(blockIdx.x * 32 + ty) * K_DIM + k0 + tx];
        __syncthreads();
#pragma unroll 8
        for (int kk = 0; kk < 32; ++kk)
            acc += As[ty][kk] * Bs[tx][kk];
        __syncthreads();
    }
    C[(size_t)row * N_DIM + blockIdx.x * 32 + tx] = acc;
}

// ---------------------------------------------------------------------------
extern "C" void kernel_launch(void* const* d_in, const int* in_sizes, int n_in,
                              void* d_out, int out_size, void* d_ws, size_t ws_size,
                              hipStream_t stream) {
    const float* x    = (const float*)d_in[0];
    const float* w    = (const float*)d_in[1];
    const float* thrp = (const float*)d_in[2];
    float* out = (float*)d_out;

    const size_t elems = (size_t)M_DIM * K_DIM;
    if (ws_size >= 2 * elems * sizeof(unsigned short)) {
        unsigned short* Ab = (unsigned short*)d_ws;
        unsigned short* Bb = Ab + elems;
        const int n8 = (int)(elems / 8);
        prune_cvt2<<<2048, 256, 0, stream>>>(x, w, Ab, Bb, thrp, n8);
        gemm_8phase<<<dim3(256), dim3(512), 0, stream>>>(Ab, Bb, out);
    } else {
        dim3 grid(N_DIM / 32, M_DIM / 32), blk(32, 32);
        gemm_f32_fallback<<<grid, blk, 0, stream>>>(x, w, out, thrp);
    }
}

// Round 8
// 143.991 us; speedup vs baseline: 1.1171x; 1.1171x over previous
//
#include <hip/hip_runtime.h>
#include <hip/hip_bf16.h>

#define M_DIM 4096
#define N_DIM 4096
#define K_DIM 4096

typedef __attribute__((ext_vector_type(8))) __bf16 bf16x8;
typedef __attribute__((ext_vector_type(8))) short short8;
typedef __attribute__((ext_vector_type(8))) unsigned short ushort8;
typedef __attribute__((ext_vector_type(4))) float f32x4;

// async global->LDS, 16B/lane (m104: dest = wave-uniform base + lane*16)
__device__ __forceinline__ void gload_lds16(const void* g, void* l) {
    __builtin_amdgcn_global_load_lds(
        (const __attribute__((address_space(1))) void*)g,
        (__attribute__((address_space(3))) void*)l,
        16, 0, 0);
}

__device__ __forceinline__ bf16x8 ld8(const unsigned short* p) {
    short8 r = *reinterpret_cast<const short8*>(p);
    return __builtin_bit_cast(bf16x8, r);
}

// ---------------------------------------------------------------------------
// fused fp32->bf16 conversion: x (pruned) and w (unpruned) in ONE launch
// ---------------------------------------------------------------------------
__global__ void prune_cvt2(const float* __restrict__ x,
                           const float* __restrict__ w,
                           unsigned short* __restrict__ xb,
                           unsigned short* __restrict__ wb,
                           const float* __restrict__ thrp, int n8) {
    const float thr = thrp[0];
    const int stride = gridDim.x * blockDim.x;
    const int total = 2 * n8;
    for (int idx = blockIdx.x * blockDim.x + threadIdx.x; idx < total; idx += stride) {
        const bool isx = idx < n8;
        const int j = isx ? idx : idx - n8;
        const float* src = isx ? x : w;
        unsigned short* dst = isx ? xb : wb;
        const float te = isx ? thr : -1.0f;   // |v| > -1 always true -> keep all
        const float4* p = reinterpret_cast<const float4*>(src) + 2 * (size_t)j;
        float4 v0 = p[0];
        float4 v1 = p[1];
        float v[8] = {v0.x, v0.y, v0.z, v0.w, v1.x, v1.y, v1.z, v1.w};
        ushort8 o;
#pragma unroll
        for (int e = 0; e < 8; ++e) {
            float f = v[e];
            f = (fabsf(f) > te) ? f : 0.0f;   // prune in fp32 (exact predicate)
            __hip_bfloat16 hh = __float2bfloat16(f);
            o[e] = *reinterpret_cast<unsigned short*>(&hh);
        }
        *reinterpret_cast<ushort8*>(dst + 8 * (size_t)j) = o;
    }
}

// ---------------------------------------------------------------------------
// C = A * B^T, 256x256 tile, BK=64, 8 waves, 16x16x32 MFMA, 4-phase/K-tile
// pipeline (R6 skeleton) with B staged TWO tiles ahead at ph3.
//
// Staging B(t+2) into the CURRENT B buffer at ph3 is race-free: B(t)'s only
// LDS reads are at ph0 (3 barriers earlier); B(t+2) has the same parity.
//
// Per-phase issue: reads 12/4/4/4 (b128), stages 0/2/2/4 (gload_lds16).
// vmcnt ledger (issues ph1: SA'01, ph2: SA'23, ph3: SB''x4):
//   invariant at ph0(t) start: outstanding = [SA(t)2,3, SB(t+1)x4] (6)
//   ph0-end vmcnt(5): lands SA(t)2   -> ph1 reads A(t)-j2       (slack 2.0 ph)
//   ph1-end vmcnt(6): lands SA(t)3   -> ph2 reads A(t)-j3       (slack 3.0 ph)
//   ph2-end vmcnt(3): lands SB(t+1)x4 + SA(t+1)0                (slack 3.0/1.5)
//   ph3-end vmcnt(6): lands SA(t+1)1 -> next ph0 reads j1+B(t+1)(slack 2.5 ph)
// Never drains to 0 in the loop.
//
// LDS per buffer: A[256][64], B[256][64], slot-swizzled:
//   element(row, logical col c) at row*64 + 8*((c>>3) ^ (row&7)) + (c&7)
// ---------------------------------------------------------------------------
__global__ __launch_bounds__(512, 2) void gemm_8phase(
        const unsigned short* __restrict__ A,
        const unsigned short* __restrict__ B,
        float* __restrict__ C) {
    __shared__ __align__(16) unsigned short lds[65536];  // 128 KB

    const int tid  = threadIdx.x;
    const int lane = tid & 63;
    const int wid  = tid >> 6;
    const int wr   = wid >> 2;   // 0..1 : 128-row strip
    const int wc   = wid & 3;    // 0..3 : 64-col strip

    // XCD-aware bijective swizzle (256 blocks / 8 XCDs)
    const int bid = blockIdx.x;
    const int swz = (bid & 7) * 32 + (bid >> 3);
    const int bm = (swz >> 4) * 256;
    const int bn = (swz & 15) * 256;

    // staging: A-half ah staged by threads [ah*256, +256); load j = rows [32j,+32)
    const int g  = tid & 255;
    const int ah = tid >> 8;
    const int arow = bm + ah * 128 + (g >> 3);
    const int acol = 8 * ((g & 7) ^ ((g >> 3) & 7));      // pre-swizzled source col
    const unsigned short* Asrc = A + (size_t)arow * K_DIM + acol;
    const int AdstE = ah * 8192 + g * 8;

    const int h = lane + 64 * wr;
    const int brow = bn + wc * 64 + (h >> 3);
    const int bcol = 8 * ((h & 7) ^ ((h >> 3) & 7));
    const unsigned short* Bsrc = B + (size_t)brow * K_DIM + bcol;
    const int BdstE = wc * 4096 + h * 8;

#define SA(dstb, j, kg) gload_lds16(Asrc + (size_t)(32*(j))*K_DIM + (kg), (dstb) + AdstE + 2048*(j))
#define SB(dstb, j, kg) gload_lds16(Bsrc + (size_t)(16*(j))*K_DIM + (kg), (dstb) + BdstE + 1024*(j))

    // fragment read offsets (row&7 == fr&7 -> swizzle slot is thread-constant)
    const int fr  = lane & 15;
    const int kq4 = lane >> 4;
    const int rowOffA = (wr * 128 + fr) * 64;
    const int rowOffB = (wc * 64 + fr) * 64;
    const int sk0 = 8 * ((kq4    ) ^ (fr & 7));
    const int sk1 = 8 * ((kq4 + 4) ^ (fr & 7));

    f32x4 acc[8][4] = {};

    bf16x8 bfr[4][2];
    // kk-split MFMA: dependency distance 8 instructions between kk0 and kk1 use
#define MFMA16(q, A00, A10, A01, A11)                                                              \
    __builtin_amdgcn_s_setprio(1);                                                                 \
    _Pragma("unroll")                                                                              \
    for (int n = 0; n < 4; ++n) {                                                                  \
        acc[2*(q)][n]   = __builtin_amdgcn_mfma_f32_16x16x32_bf16(A00, bfr[n][0], acc[2*(q)][n], 0, 0, 0);   \
        acc[2*(q)+1][n] = __builtin_amdgcn_mfma_f32_16x16x32_bf16(A10, bfr[n][0], acc[2*(q)+1][n], 0, 0, 0); \
    }                                                                                              \
    _Pragma("unroll")                                                                              \
    for (int n = 0; n < 4; ++n) {                                                                  \
        acc[2*(q)][n]   = __builtin_amdgcn_mfma_f32_16x16x32_bf16(A01, bfr[n][1], acc[2*(q)][n], 0, 0, 0);   \
        acc[2*(q)+1][n] = __builtin_amdgcn_mfma_f32_16x16x32_bf16(A11, bfr[n][1], acc[2*(q)+1][n], 0, 0, 0); \
    }                                                                                              \
    __builtin_amdgcn_s_setprio(0);

    // One K-tile body: reads (Ab,Bb); stages A(t+1)->AbN (ph1,ph2), B(t+2)->Bb
    // (ph3, race-free); pre-reads next tile's j0 A-frags from AbN at ph3.
#define TILE_BODY(Ab, Bb, AbN, kna, knb)                                                           \
    {                                                                                              \
        /* ph0: MFMA j0 (p-set); read B(t) + A(t)-j1; no stages */                                 \
        _Pragma("unroll")                                                                          \
        for (int n = 0; n < 4; ++n) {                                                              \
            bfr[n][0] = ld8((Bb) + rowOffB + n * 1024 + sk0);                                      \
            bfr[n][1] = ld8((Bb) + rowOffB + n * 1024 + sk1);                                      \
        }                                                                                          \
        bf16x8 q00 = ld8((Ab) + rowOffA + 2 * 1024 + sk0);                                         \
        bf16x8 q10 = ld8((Ab) + rowOffA + 3 * 1024 + sk0);                                         \
        bf16x8 q01 = ld8((Ab) + rowOffA + 2 * 1024 + sk1);                                         \
        bf16x8 q11 = ld8((Ab) + rowOffA + 3 * 1024 + sk1);                                         \
        MFMA16(0, p00, p10, p01, p11);                                                             \
        asm volatile("s_waitcnt vmcnt(5)" ::: "memory");                                           \
        asm volatile("s_barrier" ::: "memory");                                                    \
        /* ph1: MFMA j1 (q-set); read A(t)-j2; stage A'0,A'1 */                                    \
        bf16x8 r00 = ld8((Ab) + rowOffA + 4 * 1024 + sk0);                                         \
        bf16x8 r10 = ld8((Ab) + rowOffA + 5 * 1024 + sk0);                                         \
        bf16x8 r01 = ld8((Ab) + rowOffA + 4 * 1024 + sk1);                                         \
        bf16x8 r11 = ld8((Ab) + rowOffA + 5 * 1024 + sk1);                                         \
        SA((AbN), 0, (kna)); SA((AbN), 1, (kna));                                                  \
        MFMA16(1, q00, q10, q01, q11);                                                             \
        asm volatile("s_waitcnt vmcnt(6)" ::: "memory");                                           \
        asm volatile("s_barrier" ::: "memory");                                                    \
        /* ph2: MFMA j2 (r-set); read A(t)-j3; stage A'2,A'3 */                                    \
        bf16x8 s00 = ld8((Ab) + rowOffA + 6 * 1024 + sk0);                                         \
        bf16x8 s10 = ld8((Ab) + rowOffA + 7 * 1024 + sk0);                                         \
        bf16x8 s01 = ld8((Ab) + rowOffA + 6 * 1024 + sk1);                                         \
        bf16x8 s11 = ld8((Ab) + rowOffA + 7 * 1024 + sk1);                                         \
        SA((AbN), 2, (kna)); SA((AbN), 3, (kna));                                                  \
        MFMA16(2, r00, r10, r01, r11);                                                             \
        asm volatile("s_waitcnt vmcnt(3)" ::: "memory");                                           \
        asm volatile("s_barrier" ::: "memory");                                                    \
        /* ph3: MFMA j3 (s-set); pre-read A(t+1)-j0; stage B(t+2) -> Bb */                         \
        p00 = ld8((AbN) + rowOffA + 0 * 1024 + sk0);                                               \
        p10 = ld8((AbN) + rowOffA + 1 * 1024 + sk0);                                               \
        p01 = ld8((AbN) + rowOffA + 0 * 1024 + sk1);                                               \
        p11 = ld8((AbN) + rowOffA + 1 * 1024 + sk1);                                               \
        SB((Bb), 0, (knb)); SB((Bb), 1, (knb)); SB((Bb), 2, (knb)); SB((Bb), 3, (knb));            \
        MFMA16(3, s00, s10, s01, s11);                                                             \
        asm volatile("s_waitcnt vmcnt(6)" ::: "memory");                                           \
        asm volatile("s_barrier" ::: "memory");                                                    \
    }

    // compile-time buffer bases
    unsigned short* A0 = lds;
    unsigned short* A1 = lds + 16384;
    unsigned short* B0 = lds + 32768;
    unsigned short* B1 = lds + 49152;

    // ---- prologue: stage B(0)->B0, A(0)->A0, B(1)->B1; land B(0)+A(0)0,1;
    // leaves outstanding [SA(0)2,3, SB(1)x4] = the loop invariant.
    SB(B0, 0, 0); SB(B0, 1, 0); SB(B0, 2, 0); SB(B0, 3, 0);
    SA(A0, 0, 0); SA(A0, 1, 0); SA(A0, 2, 0); SA(A0, 3, 0);
    SB(B1, 0, 64); SB(B1, 1, 64); SB(B1, 2, 64); SB(B1, 3, 64);
    asm volatile("s_waitcnt vmcnt(6)" ::: "memory");
    asm volatile("s_barrier" ::: "memory");

    bf16x8 p00 = ld8(A0 + rowOffA + 0 * 1024 + sk0);
    bf16x8 p10 = ld8(A0 + rowOffA + 1 * 1024 + sk0);
    bf16x8 p01 = ld8(A0 + rowOffA + 0 * 1024 + sk1);
    bf16x8 p11 = ld8(A0 + rowOffA + 1 * 1024 + sk1);

    for (int t = 0; t < 64; t += 2) {
        const int kna0 = (t + 1) * 64;                     // <= 63*64, never clamps
        const int knb0 = (t + 2 < 64 ? t + 2 : 63) * 64;   // clamp: tail stages dead
        const int kna1 = (t + 2 < 64 ? t + 2 : 63) * 64;
        const int knb1 = (t + 3 < 64 ? t + 3 : 63) * 64;
        TILE_BODY(A0, B0, A1, kna0, knb0);   // even tile: read buf0, A->buf1, B(t+2)->B0
        TILE_BODY(A1, B1, A0, kna1, knb1);   // odd tile:  read buf1, A->buf0, B(t+3)->B1
    }

    asm volatile("s_waitcnt vmcnt(0)" ::: "memory");  // drain dead tail stages

    // C/D layout (m89): col = lane&15, row = (lane>>4)*4 + j
    const int crow = bm + wr * 128 + kq4 * 4;
    const int ccol = bn + wc * 64 + fr;
#pragma unroll
    for (int m = 0; m < 8; ++m)
#pragma unroll
        for (int n = 0; n < 4; ++n)
#pragma unroll
            for (int j = 0; j < 4; ++j)
                C[(size_t)(crow + m * 16 + j) * N_DIM + ccol + n * 16] = acc[m][n][j];
}

// ---------------------------------------------------------------------------
// fp32 fallback (only if ws too small)
// ---------------------------------------------------------------------------
__global__ void gemm_f32_fallback(const float* __restrict__ A,
                                  const float* __restrict__ B,
                                  float* __restrict__ C,
                                  const float* __restrict__ thrp) {
    __shared__ float As[32][33];
    __shared__ float Bs[32][33];
    const float thr = thrp[0];
    const int tx = threadIdx.x, ty = threadIdx.y;
    const int row = blockIdx.y * 32 + ty;
    float acc = 0.0f;
    for (int k0 = 0; k0 < K_DIM; k0 += 32) {
        float a = A[(size_t)row * K_DIM + k0 + tx];
        As[ty][tx] = (fabsf(a) > thr) ? a : 0.0f;
        Bs[ty][tx] = B[(size_t)(blockIdx.x * 32 + ty) * K_DIM + k0 + tx];
        __syncthreads();
#pragma unroll 8
        for (int kk = 0; kk < 32; ++kk)
            acc += As[ty][kk] * Bs[tx][kk];
        __syncthreads();
    }
    C[(size_t)row * N_DIM + blockIdx.x * 32 + tx] = acc;
}

// ---------------------------------------------------------------------------
extern "C" void kernel_launch(void* const* d_in, const int* in_sizes, int n_in,
                              void* d_out, int out_size, void* d_ws, size_t ws_size,
                              hipStream_t stream) {
    const float* x    = (const float*)d_in[0];
    const float* w    = (const float*)d_in[1];
    const float* thrp = (const float*)d_in[2];
    float* out = (float*)d_out;

    const size_t elems = (size_t)M_DIM * K_DIM;
    if (ws_size >= 2 * elems * sizeof(unsigned short)) {
        unsigned short* Ab = (unsigned short*)d_ws;
        unsigned short* Bb = Ab + elems;
        const int n8 = (int)(elems / 8);
        prune_cvt2<<<2048, 256, 0, stream>>>(x, w, Ab, Bb, thrp, n8);
        gemm_8phase<<<dim3(256), dim3(512), 0, stream>>>(Ab, Bb, out);
    } else {
        dim3 grid(N_DIM / 32, M_DIM / 32), blk(32, 32);
        gemm_f32_fallback<<<grid, blk, 0, stream>>>(x, w, out, thrp);
    }
}